// Round 14
// baseline (619.658 us; speedup 1.0000x reference)
//
#include <hip/hip_runtime.h>

// ---------------------------------------------------------------------------
// STFT-Fourier-KAN DGCNN on MI355X.
// R13 post-mortem: absmax 3.49 — the angle-major K-permutation was applied
// globally in tkan (section1 = all angles g1..4, section2 = g5 tail) but
// l4_kernel still read c4t as per-window-contiguous 2560 spans. Layer-4
// coeffs paired with wrong features -> O(1) error.
// R14: l4_kernel coefficient addressing fixed: window w section-1 at
// o*38400 + w*2048, g5 tail at o*38400 + 30720 + w*512 (boundary is
// float4-aligned; per-iteration select). Everything else = R13:
// kan<3> NT=64 (1024 blocks, 50% occ cap) + Chebyshev harmonic recurrence
// in section 1 (2 trans + 10 FMA per 4 pairs vs 8 trans).
// ---------------------------------------------------------------------------

typedef unsigned short u16;
typedef unsigned int   u32;
typedef unsigned long long u64;
typedef __attribute__((ext_vector_type(8))) _Float16 half8;
typedef __attribute__((ext_vector_type(4))) float f32x4;

__device__ __forceinline__ float bf2f(u16 u) {
  u32 v = ((u32)u) << 16;
  return __uint_as_float(v);
}
__device__ __forceinline__ u16 f2bfr(float f) {  // bf16 round-to-nearest-even
  u32 x = __float_as_uint(f);
  u32 r = x + 0x7FFFu + ((x >> 16) & 1u);
  return (u16)(r >> 16);
}
__device__ __forceinline__ u16 f2h(float f) {    // fp16 RTN bits
  _Float16 h = (_Float16)f;
  u16 r;
  __builtin_memcpy(&r, &h, 2);
  return r;
}
__device__ __forceinline__ float h2f(u16 u) {
  _Float16 h;
  __builtin_memcpy(&h, &u, 2);
  return (float)h;
}
// dtype-dispatched external load (flag wave-uniform -> scalar branch)
__device__ __forceinline__ float ldf(const void* p, size_t i, bool f32) {
  return f32 ? ((const float*)p)[i] : bf2f(((const u16*)p)[i]);
}
__device__ __forceinline__ u64 minu64(u64 a, u64 b) { return a < b ? a : b; }

// ---------------- workspace layout (bytes) ----------------
#define NBR_OFF   ((size_t)0)                       // int32 [163840]       655,360
#define FLAG_OFF  ((size_t)917504)                  // int32 [1]
#define XG_OFF    ((size_t)(1u << 20))              // f32 [8][2048]         65,536
#define L4P_OFF   (((size_t)(1u << 20)) + 131072)   // f32 [8][15][240]     115,200
#define C1T_OFF   (((size_t)(1u << 20)) + 524288)   // fp16 [64][64]          8,192
#define C2T_OFF   (((size_t)(1u << 20)) + 589824)   // fp16 [128][1120]     286,720
#define C3T_OFF   ((size_t)(2u << 20))              // fp16 [1024][2240]  4,587,520
#define C4T_OFF   ((size_t)(7u << 20))              // f32  [40][38400]   6,144,000
#define SEGP_OFF  ((size_t)(13u << 20))             // f32 [2][64][1024]    524,288
#define X1_OFF    ((size_t)(14u << 20))             // f32 [8192][128]    4,194,304
#define H1_OFF    ((size_t)(19u << 20))             // f32 [163840][64]  41,943,040
#define X_OFF     ((size_t)(19u << 20))             // f32 [8192][1024]  (overlaps dead h1)
#define H2_OFF    ((size_t)(61u << 20))             // fp16 [163840][128] 41,943,040
// peak ~103 MB

// ---------------- dtype detector -------------------------------------------
__global__ void detect_kernel(const void* __restrict__ pos,
                              int* __restrict__ flag) {
  int t = threadIdx.x;  // 64 threads
  float a = fabsf(((const float*)pos)[t]);
  bool ok = (a > 1.0e-3f && a < 100.0f);
  unsigned long long m = __ballot(ok);
  if (t == 0) *flag = (__popcll(m) >= 32) ? 1 : 0;  // 1 = fp32 externals
}

// ---------------- coeff transpose: c[part][o][w][i][g] -> ct[o][f] ----------
// Angle-major global order: p < 4*NA: aa=p>>2, g=(p&3)+1 ;
// p in [4*NA,5*NA): aa=p-4*NA, g=5. f = 2*p + part. Pad f>=Kt with zeros.
__global__ void tkan_kernel(const void* __restrict__ src, void* __restrict__ dst,
                            int dout, int nw, int W, int total, int KPAD,
                            int outf32, const int* __restrict__ dfl) {
  int id = blockIdx.x * 256 + threadIdx.x;
  if (id >= total) return;
  const bool f32 = (*dfl != 0);
  int o = id / KPAD, f = id % KPAD;
  int NA = nw * W;
  int Kt = NA * 10;
  float v = 0.f;
  if (f < Kt) {
    int part = f & 1, p = f >> 1;
    int aa, gg;
    if (p < 4 * NA) { aa = p >> 2;      gg = p & 3; }
    else            { aa = p - 4 * NA;  gg = 4;     }
    int i = aa % W, w = aa / W;
    int OS = NA * 5;
    size_t sidx = (size_t)part * (dout * OS) + (size_t)o * OS + w * (W * 5) + i * 5 + gg;
    v = ldf(src, sidx, f32);
  }
  if (outf32) ((float*)dst)[id] = v;
  else        ((u16*)dst)[id] = f2h(v);
}

// ---------------- brute-force kNN: one wave per query -----------------------
__global__ __launch_bounds__(256) void knn_kernel(const void* __restrict__ pos,
                                                  int* __restrict__ nbr,
                                                  const int* __restrict__ dfl) {
  __shared__ float px[1024], py[1024], pz[1024];
  const bool f32 = (*dfl != 0);
  const int t = threadIdx.x;
  const int b = blockIdx.y;
  const int base = b << 10;
  for (int j = t; j < 1024; j += 256) {
    size_t pidx = (size_t)(base + j) * 3;
    px[j] = ldf(pos, pidx, f32);
    py[j] = ldf(pos, pidx + 1, f32);
    pz[j] = ldf(pos, pidx + 2, f32);
  }
  __syncthreads();
  const int wv = t >> 6, lane = t & 63;
  const int q = blockIdx.x * 4 + wv;
  const float qx = px[q], qy = py[q], qz = pz[q];
  u64 key[16];
#pragma unroll
  for (int s = 0; s < 16; ++s) {
    const int j = s * 64 + lane;
    float dx = qx - px[j], dy = qy - py[j], dz = qz - pz[j];
    float d = __fadd_rn(__fadd_rn(__fmul_rn(dx, dx), __fmul_rn(dy, dy)),
                        __fmul_rn(dz, dz));
    key[s] = (j == q) ? ~0ull
                      : ((((u64)__float_as_uint(d)) << 32) | (u32)j);
  }
  const int obase = (base + q) * 20;
  for (int k = 0; k < 20; ++k) {
    u64 m = key[0];
#pragma unroll
    for (int s = 1; s < 16; ++s) m = minu64(m, key[s]);
#pragma unroll
    for (int off = 32; off >= 1; off >>= 1) {
      u32 lo = (u32)m, hi = (u32)(m >> 32);
      lo = __shfl_xor(lo, off, 64);
      hi = __shfl_xor(hi, off, 64);
      m = minu64(m, (((u64)hi) << 32) | lo);
    }
    if (lane == 0) nbr[obase + k] = (int)(u32)m;
#pragma unroll
    for (int s = 0; s < 16; ++s)
      if (key[s] == m) key[s] = ~0ull;  // idx embedded -> unique, safe
  }
}

// ---------------- MFMA KAN layer, fp16 slab + Chebyshev harmonics -----------
template <int L>
__global__ __launch_bounds__(256, 4) void kan_kernel(
    const void* __restrict__ in_, const int* __restrict__ nbr,
    const void* __restrict__ pos, const u16* __restrict__ ct,
    const void* __restrict__ bias, void* __restrict__ out_,
    const int* __restrict__ dfl) {
  constexpr int W    = (L == 1) ? 3  : (L == 2) ? 16  : 32;
  constexpr int S    = (L == 1) ? 3  : (L == 2) ? 8   : 16;
  constexpr int DIN  = (L == 1) ? 6  : (L == 2) ? 64  : 128;
  constexpr int DOUT = (L == 1) ? 64 : (L == 2) ? 128 : 1024;
  constexpr int NT   = (L == 1) ? 64 : (L == 2) ? 128 : 64;   // L3: 64 -> 1024 blocks
  constexpr int NW   = (DIN - W) / S + 1;
  constexpr int NA   = NW * W;                      // angles
  constexpr int NPAIR = NA * 5;
  constexpr int S1P  = NA * 4;                      // section-1 pairs (g=1..4)
  constexpr int KROW  = (L == 1) ? 64 : NPAIR * 2;  // ct row stride (padded L1)
  constexpr int NCH   = KROW / 32;
  constexpr int NB    = NT / 16;
  constexpr int RW    = (L == 1) ? 64 : 32;         // rows per wave
  constexpr int MB    = RW / 16;
  constexpr int PSTH  = DIN + 4;                    // slab stride (halves)
  constexpr int LGW   = (W == 16) ? 4 : 5;          // log2(W) for L2/L3

  __shared__ float hamS[(L == 1) ? 1 : W];
  __shared__ float wT1[(L == 1) ? 32 : 1];          // L1 tables (padded K=64)
  __shared__ int   hT1[(L == 1) ? 32 : 1];
  __shared__ u16   slab[(L == 1) ? 2 : 4 * RW * PSTH];

  const bool f32 = (*dfl != 0);
  const float* inF = (const float*)in_;
  const int t = threadIdx.x;
  if constexpr (L == 1) {
    if (t < 32) {
      float wv_ = 0.f; int hx = 0;
      if (t < NPAIR) {                              // angle-major mapping
        int aa, gg;
        if (t < S1P) { aa = t >> 2;   gg = t & 3; }
        else         { aa = t - S1P;  gg = 4;     }
        int i = aa % W;
        float hm = 0.54f - 0.46f * cospif(2.0f * (float)i / (float)(W - 1));
        wv_ = hm * (float)(gg + 1);
        hx = aa;                                    // L1 uses aa directly
      }
      wT1[t] = wv_; hT1[t] = hx;
    }
  } else {
    if (t < W) hamS[t] = 0.54f - 0.46f * cospif(2.0f * (float)t / (float)(W - 1));
  }
  __syncthreads();

  const int tile = blockIdx.x;
  const int ncol0 = blockIdx.y * NT;
  const int lane = t & 63, wv = t >> 6;
  const int m16 = lane & 15, kb = lane >> 4;
  const int rowbase = tile * (4 * RW) + wv * RW;
  u16* myslab = &slab[(L == 1) ? 0 : wv * RW * PSTH];

  // ---- stage wave-private fp16 slab (L>=2), coalesced float4 reads ----
  if constexpr (L >= 2) {
    constexpr int F4R = DIN / 4;
    constexpr int TOT = RW * F4R;
    for (int i = lane; i < TOT; i += 64) {
      const int r = i / F4R, c4 = i % F4R;
      const float4 v = *(const float4*)(inF + (size_t)(rowbase + r) * DIN + c4 * 4);
      ushort4 hv;
      hv.x = f2h(v.x); hv.y = f2h(v.y); hv.z = f2h(v.z); hv.w = f2h(v.w);
      *(ushort4*)(myslab + r * PSTH + c4 * 4) = hv;
    }
  }

  f32x4 acc[MB][NB];
#pragma unroll
  for (int mb = 0; mb < MB; ++mb)
#pragma unroll
    for (int nb = 0; nb < NB; ++nb) {
      acc[mb][nb][0] = 0.f; acc[mb][nb][1] = 0.f;
      acc[mb][nb][2] = 0.f; acc[mb][nb][3] = 0.f;
    }

  for (int c = 0; c < NCH; ++c) {
    // ---- issue B loads first (latency covered by the trans chain) ----
    half8 bv[NB];
#pragma unroll
    for (int nb = 0; nb < NB; ++nb)
      bv[nb] = *(const half8*)(ct +
          (size_t)(ncol0 + nb * 16 + m16) * KROW + c * 32 + kb * 8);
    const int pg0 = c * 16 + kb * 4;
    half8 af[MB];
    if constexpr (L == 1) {
      float wm[4]; int hx[4]; bool val[4];
#pragma unroll
      for (int u = 0; u < 4; ++u) {
        const int pg = pg0 + u;
        wm[u] = wT1[pg]; hx[u] = hT1[pg]; val[u] = (pg < NPAIR);
      }
#pragma unroll
      for (int mb = 0; mb < MB; ++mb) {
        const int row = rowbase + mb * 16 + m16;
        const int pt = row / 20;
        const int cloud = pt >> 10, ci = pt & 1023;
        const int cb = cloud << 10;
        const int jl = nbr[row];
#pragma unroll
        for (int u = 0; u < 4; ++u) {
          float cs = 0.f, sn = 0.f;
          if (val[u]) {
            const int aa = hx[u];
            float v;
            if (aa < 3) {
              v = ldf(pos, (size_t)(cb + ci) * 3 + aa, f32);
            } else {
              const int cc2 = aa - 3;
              v = ldf(pos, (size_t)(cb + jl) * 3 + cc2, f32) -
                  ldf(pos, (size_t)(cb + ci) * 3 + cc2, f32);
            }
            const float ang = v * wm[u];
            cs = __cosf(ang); sn = __sinf(ang);
          }
          af[mb][2 * u]     = (_Float16)cs;
          af[mb][2 * u + 1] = (_Float16)sn;
        }
      }
    } else if (pg0 < S1P) {
      // section 1: lane's 4 pairs = ONE angle, g=1..4 -> Chebyshev recurrence
      const int aa = pg0 >> 2;
      const int i = aa & (W - 1), w = aa >> LGW;
      const int hidx = S * w + i;
      const float hm = hamS[i];
#pragma unroll
      for (int mb = 0; mb < MB; ++mb) {
        const u16* rp = myslab + (mb * 16 + m16) * PSTH;
        const float th = h2f(rp[hidx]) * hm;
        const float c1 = __cosf(th), s1 = __sinf(th);
        const float tc = 2.0f * c1;
        const float c2 = tc * c1 - 1.0f, s2 = tc * s1;
        const float c3 = tc * c2 - c1,   s3 = tc * s2 - s1;
        const float c4 = tc * c3 - c2,   s4 = tc * s3 - s2;
        af[mb][0] = (_Float16)c1; af[mb][1] = (_Float16)s1;
        af[mb][2] = (_Float16)c2; af[mb][3] = (_Float16)s2;
        af[mb][4] = (_Float16)c3; af[mb][5] = (_Float16)s3;
        af[mb][6] = (_Float16)c4; af[mb][7] = (_Float16)s4;
      }
    } else {
      // section 2: g=5 tail, 4 distinct angles, direct cos/sin
      const int q0 = pg0 - S1P;
      float wm[4]; int hx[4];
#pragma unroll
      for (int u = 0; u < 4; ++u) {
        const int aa = q0 + u;
        const int i = aa & (W - 1), w = aa >> LGW;
        hx[u] = S * w + i;
        wm[u] = hamS[i] * 5.0f;
      }
#pragma unroll
      for (int mb = 0; mb < MB; ++mb) {
        const u16* rp = myslab + (mb * 16 + m16) * PSTH;
#pragma unroll
        for (int u = 0; u < 4; ++u) {
          const float ang = h2f(rp[hx[u]]) * wm[u];
          af[mb][2 * u]     = (_Float16)__cosf(ang);
          af[mb][2 * u + 1] = (_Float16)__sinf(ang);
        }
      }
    }
#pragma unroll
    for (int nb = 0; nb < NB; ++nb)
#pragma unroll
      for (int mb = 0; mb < MB; ++mb)
        acc[mb][nb] = __builtin_amdgcn_mfma_f32_16x16x32_f16(
            af[mb], bv[nb], acc[mb][nb], 0, 0, 0);
  }
  // ---- epilogue: D row=(lane>>4)*4+r, col=lane&15 ; + bias ----
#pragma unroll
  for (int mb = 0; mb < MB; ++mb) {
    const int rowb = rowbase + mb * 16 + kb * 4;
#pragma unroll
    for (int nb = 0; nb < NB; ++nb) {
      const int col = ncol0 + nb * 16 + m16;
      const float bsv = ldf(bias, col, f32);
#pragma unroll
      for (int r = 0; r < 4; ++r) {
        const float ov = acc[mb][nb][r] + bsv;
        if constexpr (L == 2)
          ((u16*)out_)[(size_t)(rowb + r) * DOUT + col] = f2h(ov);
        else
          ((float*)out_)[(size_t)(rowb + r) * DOUT + col] = ov;
      }
    }
  }
}

// ---------------- max over K=20 neighbors (fp16 in, f32 out) ----------------
__global__ void maxk_kernel(const u16* __restrict__ h2, float* __restrict__ x1) {
  int id = blockIdx.x * 256 + threadIdx.x;  // 8192*128 total
  int pcol = id & 127, pt = id >> 7;
  const u16* hp = h2 + (size_t)pt * 2560 + pcol;
  float m = -3.0e38f;
#pragma unroll
  for (int kk = 0; kk < 20; ++kk) m = fmaxf(m, h2f(hp[kk * 128]));
  x1[(size_t)pt * 128 + pcol] = m;
}

// ---------------- segment max + mean: partial (256 blocks) + combine --------
__global__ void seg1_kernel(const float* __restrict__ x,
                            float* __restrict__ pmax,
                            float* __restrict__ psum) {
  const int t = threadIdx.x;
  const int by = blockIdx.y;            // b*8 + rchunk
  const int b = by >> 3, rc = by & 7;
  const int col = blockIdx.x * 256 + t;
  const float* xp = x + ((size_t)(b << 10) + rc * 128) * 1024 + col;
  float m = -3.0e38f, s = 0.f;
  for (int r = 0; r < 128; ++r) {
    float v = xp[(size_t)r * 1024];
    m = fmaxf(m, v);
    s += v;
  }
  pmax[(size_t)by * 1024 + col] = m;
  psum[(size_t)by * 1024 + col] = s;
}

__global__ void seg2_kernel(const float* __restrict__ pmax,
                            const float* __restrict__ psum,
                            float* __restrict__ xg) {
  const int id = blockIdx.x * 256 + threadIdx.x;  // 8192
  const int b = id >> 10, col = id & 1023;
  float m = -3.0e38f, s = 0.f;
#pragma unroll
  for (int rc = 0; rc < 8; ++rc) {
    m = fmaxf(m, pmax[(size_t)(b * 8 + rc) * 1024 + col]);
    s += psum[(size_t)(b * 8 + rc) * 1024 + col];
  }
  xg[b * 2048 + col] = m;
  xg[b * 2048 + 1024 + col] = s * (1.0f / 1024.0f);
}

// ---------------- layer 4 partials: one WG per (window, batch) --------------
// c4t GLOBAL layout (angle-major): window w section-1 (g1..4 quads) at
// o*38400 + w*2048 ; g5 tail at o*38400 + 30720 + w*512. F mirrors the
// within-window order: F[8t+2g+part] (t<256), F[2048+2t+part].
__global__ __launch_bounds__(256) void l4_kernel(const float* __restrict__ xg,
                                                 const float* __restrict__ c4t,
                                                 float* __restrict__ part) {
  __shared__ float F[2560];
  const int t = threadIdx.x;
  const int w = blockIdx.x, b = blockIdx.y;
  const float xv = xg[b * 2048 + w * 128 + t];
  const float hm = 0.54f - 0.46f * cospif(2.0f * (float)t / 255.0f);
  const float aa = xv * hm;
  const float c1 = __cosf(aa), s1 = __sinf(aa);
  const float tc = 2.0f * c1;
  const float c2 = tc * c1 - 1.0f, s2 = tc * s1;
  const float c3 = tc * c2 - c1,   s3 = tc * s2 - s1;
  const float c4 = tc * c3 - c2,   s4 = tc * s3 - s2;
  const float a5 = aa * 5.0f;
  F[t * 8]     = c1; F[t * 8 + 1] = s1;
  F[t * 8 + 2] = c2; F[t * 8 + 3] = s2;
  F[t * 8 + 4] = c3; F[t * 8 + 5] = s3;
  F[t * 8 + 6] = c4; F[t * 8 + 7] = s4;
  F[2048 + t * 2]     = __cosf(a5);
  F[2048 + t * 2 + 1] = __sinf(a5);
  __syncthreads();
  if (t < 240) {
    const int o = t % 40, s = t / 40;
    const int f0 = s * 432;
    const int f1 = (f0 + 432 < 2560) ? (f0 + 432) : 2560;
    const float* cp1 = c4t + (size_t)o * 38400 + w * 2048;          // sec 1
    const float* cp2 = c4t + (size_t)o * 38400 + 30720 + w * 512;   // g5 tail
    float acc = 0.f;
    for (int f = f0; f < f1; f += 4) {   // 2048 boundary is float4-aligned
      const float* cpf = (f < 2048) ? (cp1 + f) : (cp2 + (f - 2048));
      const float4 cv = *(const float4*)cpf;
      const float4 fa = *(const float4*)&F[f];
      acc += fa.x * cv.x + fa.y * cv.y + fa.z * cv.z + fa.w * cv.w;
    }
    part[((b * 15 + w) * 6 + s) * 40 + o] = acc;
  }
}

__global__ void outred_kernel(const float* __restrict__ part,
                              const void* __restrict__ b4,
                              void* __restrict__ outp,
                              const int* __restrict__ dfl) {
  int t = threadIdx.x;
  if (t >= 320) return;
  const bool f32 = (*dfl != 0);
  int b = t / 40, o = t % 40;
  float s = ldf(b4, o, f32);
  for (int w = 0; w < 15; ++w)
#pragma unroll
    for (int sl = 0; sl < 6; ++sl)
      s += part[((b * 15 + w) * 6 + sl) * 40 + o];
  if (f32) ((float*)outp)[t] = s;
  else     ((u16*)outp)[t] = f2bfr(s);
}

// ---------------------------------------------------------------------------
extern "C" void kernel_launch(void* const* d_in, const int* in_sizes, int n_in,
                              void* d_out, int out_size, void* d_ws,
                              size_t ws_size, hipStream_t stream) {
  (void)in_sizes; (void)n_in; (void)out_size; (void)ws_size;
  const void* pos = d_in[0];
  // d_in[1] = batch (int32) -- clouds are sorted equal-size, used implicitly
  const void* c1 = d_in[2];
  const void* b1 = d_in[3];
  const void* c2 = d_in[4];
  const void* b2 = d_in[5];
  const void* c3 = d_in[6];
  const void* b3 = d_in[7];
  const void* c4 = d_in[8];
  const void* b4 = d_in[9];

  char* ws = (char*)d_ws;
  int* nbr   = (int*)(ws + NBR_OFF);
  int* flag  = (int*)(ws + FLAG_OFF);
  float* xg  = (float*)(ws + XG_OFF);
  float* l4p = (float*)(ws + L4P_OFF);
  u16* c1t   = (u16*)(ws + C1T_OFF);
  u16* c2t   = (u16*)(ws + C2T_OFF);
  u16* c3t   = (u16*)(ws + C3T_OFF);
  float* c4t = (float*)(ws + C4T_OFF);
  float* pmax = (float*)(ws + SEGP_OFF);
  float* psum = (float*)(ws + SEGP_OFF + 262144);
  float* x1  = (float*)(ws + X1_OFF);
  float* h1  = (float*)(ws + H1_OFF);
  float* x   = (float*)(ws + X_OFF);
  u16* h2    = (u16*)(ws + H2_OFF);

  detect_kernel<<<1, 64, 0, stream>>>(pos, flag);

  tkan_kernel<<<16, 256, 0, stream>>>(c1, c1t, 64, 2, 3, 64 * 64, 64, 0, flag);
  tkan_kernel<<<560, 256, 0, stream>>>(c2, c2t, 128, 7, 16, 128 * 1120, 1120, 0, flag);
  tkan_kernel<<<8960, 256, 0, stream>>>(c3, c3t, 1024, 7, 32, 1024 * 2240, 2240, 0, flag);
  tkan_kernel<<<6000, 256, 0, stream>>>(c4, c4t, 40, 15, 256, 40 * 38400, 38400, 1, flag);

  knn_kernel<<<dim3(256, 8), 256, 0, stream>>>(pos, nbr, flag);

  kan_kernel<1><<<640, 256, 0, stream>>>(nullptr, nbr, pos, c1t, b1, h1, flag);
  kan_kernel<2><<<1280, 256, 0, stream>>>(h1, nullptr, nullptr, c2t, b2, h2, flag);
  maxk_kernel<<<4096, 256, 0, stream>>>(h2, x1);
  kan_kernel<3><<<dim3(64, 16), 256, 0, stream>>>(x1, nullptr, nullptr, c3t, b3, x, flag);

  seg1_kernel<<<dim3(4, 64), 256, 0, stream>>>(x, pmax, psum);
  seg2_kernel<<<32, 256, 0, stream>>>(pmax, psum, xg);
  l4_kernel<<<dim3(15, 8), 256, 0, stream>>>(xg, c4t, l4p);
  outred_kernel<<<1, 320, 0, stream>>>(l4p, b4, d_out, flag);
}

// Round 15
// 373.448 us; speedup vs baseline: 1.6593x; 1.6593x over previous
//
#include <hip/hip_runtime.h>

// ---------------------------------------------------------------------------
// STFT-Fourier-KAN DGCNN on MI355X.
// R14 post-mortem: kan<2> = 300us, WRITE_SIZE 178MB for 42MB h2 (4.2x
// partial-line write amplification from 2B/lane scattered stores) -> pure
// store-drain bound (Mfma 6%, VALU 10%, 740 GB/s).
// R15: fuse reductions into GEMM epilogues; kill big intermediates.
//  - kan<2>+maxpool fused: RW=80 (=4 points x K20); C-tile -> dead slab LDS,
//    max over 20 rows, write x1 fp16 (2MB). h2 + maxk gone.
//  - kan<3>+segment fused: in-register max/sum + kb-butterfly -> 32-row
//    pmax/psum partials. x + seg1 gone; seg2 reduces 32 chunks.
//  - kan<1> writes h1 fp16 (bit-identical to old f32->f2h-at-staging) via
//    LDS re-stage + contiguous uint4 copies (full-line writes).
// ---------------------------------------------------------------------------

typedef unsigned short u16;
typedef unsigned int   u32;
typedef unsigned long long u64;
typedef __attribute__((ext_vector_type(8))) _Float16 half8;
typedef __attribute__((ext_vector_type(4))) float f32x4;

__device__ __forceinline__ float bf2f(u16 u) {
  u32 v = ((u32)u) << 16;
  return __uint_as_float(v);
}
__device__ __forceinline__ u16 f2bfr(float f) {  // bf16 round-to-nearest-even
  u32 x = __float_as_uint(f);
  u32 r = x + 0x7FFFu + ((x >> 16) & 1u);
  return (u16)(r >> 16);
}
__device__ __forceinline__ u16 f2h(float f) {    // fp16 RTN bits
  _Float16 h = (_Float16)f;
  u16 r;
  __builtin_memcpy(&r, &h, 2);
  return r;
}
__device__ __forceinline__ float h2f(u16 u) {
  _Float16 h;
  __builtin_memcpy(&h, &u, 2);
  return (float)h;
}
// dtype-dispatched external load (flag wave-uniform -> scalar branch)
__device__ __forceinline__ float ldf(const void* p, size_t i, bool f32) {
  return f32 ? ((const float*)p)[i] : bf2f(((const u16*)p)[i]);
}
__device__ __forceinline__ u64 minu64(u64 a, u64 b) { return a < b ? a : b; }

// ---------------- workspace layout (bytes) ----------------
#define NBR_OFF   ((size_t)0)                       // int32 [163840]       655,360
#define FLAG_OFF  ((size_t)917504)                  // int32 [1]
#define XG_OFF    ((size_t)(1u << 20))              // f32 [8][2048]         65,536
#define L4P_OFF   (((size_t)(1u << 20)) + 131072)   // f32 [8][15][240]     115,200
#define C1T_OFF   (((size_t)(1u << 20)) + 524288)   // fp16 [64][64]          8,192
#define C2T_OFF   (((size_t)(1u << 20)) + 589824)   // fp16 [128][1120]     286,720
#define C3T_OFF   ((size_t)(2u << 20))              // fp16 [1024][2240]  4,587,520
#define C4T_OFF   ((size_t)(7u << 20))              // f32  [40][38400]   6,144,000
#define PMAX_OFF  ((size_t)(13u << 20))             // f32 [256][1024]    1,048,576
#define PSUM_OFF  ((size_t)(14u << 20))             // f32 [256][1024]    1,048,576
#define X1_OFF    ((size_t)(15u << 20))             // fp16 [8192][128]   2,097,152
#define H1_OFF    ((size_t)(18u << 20))             // fp16 [163840][64] 20,971,520
// peak ~39 MB

// ---------------- dtype detector -------------------------------------------
__global__ void detect_kernel(const void* __restrict__ pos,
                              int* __restrict__ flag) {
  int t = threadIdx.x;  // 64 threads
  float a = fabsf(((const float*)pos)[t]);
  bool ok = (a > 1.0e-3f && a < 100.0f);
  unsigned long long m = __ballot(ok);
  if (t == 0) *flag = (__popcll(m) >= 32) ? 1 : 0;  // 1 = fp32 externals
}

// ---------------- coeff transpose: c[part][o][w][i][g] -> ct[o][f] ----------
// Angle-major global order: p < 4*NA: aa=p>>2, g=(p&3)+1 ;
// p in [4*NA,5*NA): aa=p-4*NA, g=5. f = 2*p + part. Pad f>=Kt with zeros.
__global__ void tkan_kernel(const void* __restrict__ src, void* __restrict__ dst,
                            int dout, int nw, int W, int total, int KPAD,
                            int outf32, const int* __restrict__ dfl) {
  int id = blockIdx.x * 256 + threadIdx.x;
  if (id >= total) return;
  const bool f32 = (*dfl != 0);
  int o = id / KPAD, f = id % KPAD;
  int NA = nw * W;
  int Kt = NA * 10;
  float v = 0.f;
  if (f < Kt) {
    int part = f & 1, p = f >> 1;
    int aa, gg;
    if (p < 4 * NA) { aa = p >> 2;      gg = p & 3; }
    else            { aa = p - 4 * NA;  gg = 4;     }
    int i = aa % W, w = aa / W;
    int OS = NA * 5;
    size_t sidx = (size_t)part * (dout * OS) + (size_t)o * OS + w * (W * 5) + i * 5 + gg;
    v = ldf(src, sidx, f32);
  }
  if (outf32) ((float*)dst)[id] = v;
  else        ((u16*)dst)[id] = f2h(v);
}

// ---------------- brute-force kNN: one wave per query -----------------------
__global__ __launch_bounds__(256) void knn_kernel(const void* __restrict__ pos,
                                                  int* __restrict__ nbr,
                                                  const int* __restrict__ dfl) {
  __shared__ float px[1024], py[1024], pz[1024];
  const bool f32 = (*dfl != 0);
  const int t = threadIdx.x;
  const int b = blockIdx.y;
  const int base = b << 10;
  for (int j = t; j < 1024; j += 256) {
    size_t pidx = (size_t)(base + j) * 3;
    px[j] = ldf(pos, pidx, f32);
    py[j] = ldf(pos, pidx + 1, f32);
    pz[j] = ldf(pos, pidx + 2, f32);
  }
  __syncthreads();
  const int wv = t >> 6, lane = t & 63;
  const int q = blockIdx.x * 4 + wv;
  const float qx = px[q], qy = py[q], qz = pz[q];
  u64 key[16];
#pragma unroll
  for (int s = 0; s < 16; ++s) {
    const int j = s * 64 + lane;
    float dx = qx - px[j], dy = qy - py[j], dz = qz - pz[j];
    float d = __fadd_rn(__fadd_rn(__fmul_rn(dx, dx), __fmul_rn(dy, dy)),
                        __fmul_rn(dz, dz));
    key[s] = (j == q) ? ~0ull
                      : ((((u64)__float_as_uint(d)) << 32) | (u32)j);
  }
  const int obase = (base + q) * 20;
  for (int k = 0; k < 20; ++k) {
    u64 m = key[0];
#pragma unroll
    for (int s = 1; s < 16; ++s) m = minu64(m, key[s]);
#pragma unroll
    for (int off = 32; off >= 1; off >>= 1) {
      u32 lo = (u32)m, hi = (u32)(m >> 32);
      lo = __shfl_xor(lo, off, 64);
      hi = __shfl_xor(hi, off, 64);
      m = minu64(m, (((u64)hi) << 32) | lo);
    }
    if (lane == 0) nbr[obase + k] = (int)(u32)m;
#pragma unroll
    for (int s = 0; s < 16; ++s)
      if (key[s] == m) key[s] = ~0ull;  // idx embedded -> unique, safe
  }
}

// ---------------- MFMA KAN layer, fused epilogues ---------------------------
// L1: pos-gather A, out h1 fp16 via LDS re-stage + contiguous uint4 copy.
// L2: fp16 slab in, RW=80 (4 points), maxpool-over-20 in dead slab, out x1.
// L3: fp16 slab in, RW=32, in-register+butterfly max/sum -> pmax/psum.
template <int L>
__global__ __launch_bounds__(256, (L == 2) ? 3 : 4) void kan_kernel(
    const void* __restrict__ in_, const int* __restrict__ nbr,
    const void* __restrict__ pos, const u16* __restrict__ ct,
    const void* __restrict__ bias, void* __restrict__ out_,
    float* __restrict__ pmax, float* __restrict__ psum,
    const int* __restrict__ dfl) {
  constexpr int W    = (L == 1) ? 3  : (L == 2) ? 16  : 32;
  constexpr int S    = (L == 1) ? 3  : (L == 2) ? 8   : 16;
  constexpr int DIN  = (L == 1) ? 6  : (L == 2) ? 64  : 128;
  constexpr int NT   = 64;                          // all layers: 64-col tiles
  constexpr int NW   = (DIN - W) / S + 1;
  constexpr int NA   = NW * W;                      // angles
  constexpr int NPAIR = NA * 5;
  constexpr int S1P  = NA * 4;                      // section-1 pairs (g=1..4)
  constexpr int KROW  = (L == 1) ? 64 : NPAIR * 2;  // ct row stride (padded L1)
  constexpr int NCH   = KROW / 32;
  constexpr int NB    = NT / 16;                    // 4
  constexpr int RW    = (L == 1) ? 64 : (L == 2) ? 80 : 32;  // rows per wave
  constexpr int MB    = RW / 16;
  constexpr int PSTH  = DIN + 8;                    // slab stride (halves, 16B-mult)
  constexpr int LGW   = (W == 16) ? 4 : 5;          // log2(W) for L2/L3

  __shared__ float hamS[(L == 1) ? 1 : W];
  __shared__ float wT1[(L == 1) ? 32 : 1];          // L1 tables (padded K=64)
  __shared__ int   hT1[(L == 1) ? 32 : 1];
  __shared__ u16   slab[(L == 1) ? 2 : 4 * RW * PSTH];
  __shared__ u16   stage1[(L == 1) ? 4 * 64 * 64 : 2];

  const bool f32 = (*dfl != 0);
  const u16* inH = (const u16*)in_;
  const int t = threadIdx.x;
  if constexpr (L == 1) {
    if (t < 32) {
      float wv_ = 0.f; int hx = 0;
      if (t < NPAIR) {                              // angle-major mapping
        int aa, gg;
        if (t < S1P) { aa = t >> 2;   gg = t & 3; }
        else         { aa = t - S1P;  gg = 4;     }
        int i = aa % W;
        float hm = 0.54f - 0.46f * cospif(2.0f * (float)i / (float)(W - 1));
        wv_ = hm * (float)(gg + 1);
        hx = aa;                                    // L1 uses aa directly
      }
      wT1[t] = wv_; hT1[t] = hx;
    }
  } else {
    if (t < W) hamS[t] = 0.54f - 0.46f * cospif(2.0f * (float)t / (float)(W - 1));
  }
  __syncthreads();

  const int tile = blockIdx.x;
  const int ncol0 = blockIdx.y * NT;
  const int lane = t & 63, wv = t >> 6;
  const int m16 = lane & 15, kb = lane >> 4;
  const int rowbase = tile * (4 * RW) + wv * RW;
  u16* myslab = &slab[(L == 1) ? 0 : wv * RW * PSTH];

  // ---- stage wave-private fp16 slab (L>=2): uint4 = 8 halves ----
  if constexpr (L >= 2) {
    constexpr int F16R = DIN / 8;
    constexpr int TOT = RW * F16R;
    for (int i = lane; i < TOT; i += 64) {
      const int r = i / F16R, c8 = i % F16R;
      *(uint4*)(myslab + r * PSTH + c8 * 8) =
          *(const uint4*)(inH + (size_t)(rowbase + r) * DIN + c8 * 8);
    }
  }

  f32x4 acc[MB][NB];
#pragma unroll
  for (int mb = 0; mb < MB; ++mb)
#pragma unroll
    for (int nb = 0; nb < NB; ++nb) {
      acc[mb][nb][0] = 0.f; acc[mb][nb][1] = 0.f;
      acc[mb][nb][2] = 0.f; acc[mb][nb][3] = 0.f;
    }

  for (int c = 0; c < NCH; ++c) {
    // ---- issue B loads first (latency covered by the trans chain) ----
    half8 bv[NB];
#pragma unroll
    for (int nb = 0; nb < NB; ++nb)
      bv[nb] = *(const half8*)(ct +
          (size_t)(ncol0 + nb * 16 + m16) * KROW + c * 32 + kb * 8);
    const int pg0 = c * 16 + kb * 4;
    half8 af[MB];
    if constexpr (L == 1) {
      float wm[4]; int hx[4]; bool val[4];
#pragma unroll
      for (int u = 0; u < 4; ++u) {
        const int pg = pg0 + u;
        wm[u] = wT1[pg]; hx[u] = hT1[pg]; val[u] = (pg < NPAIR);
      }
#pragma unroll
      for (int mb = 0; mb < MB; ++mb) {
        const int row = rowbase + mb * 16 + m16;
        const int pt = row / 20;
        const int cloud = pt >> 10, ci = pt & 1023;
        const int cb = cloud << 10;
        const int jl = nbr[row];
#pragma unroll
        for (int u = 0; u < 4; ++u) {
          float cs = 0.f, sn = 0.f;
          if (val[u]) {
            const int aa = hx[u];
            float v;
            if (aa < 3) {
              v = ldf(pos, (size_t)(cb + ci) * 3 + aa, f32);
            } else {
              const int cc2 = aa - 3;
              v = ldf(pos, (size_t)(cb + jl) * 3 + cc2, f32) -
                  ldf(pos, (size_t)(cb + ci) * 3 + cc2, f32);
            }
            const float ang = v * wm[u];
            cs = __cosf(ang); sn = __sinf(ang);
          }
          af[mb][2 * u]     = (_Float16)cs;
          af[mb][2 * u + 1] = (_Float16)sn;
        }
      }
    } else if (pg0 < S1P) {
      // section 1: one angle, g=1..4 -> Chebyshev recurrence
      const int aa = pg0 >> 2;
      const int i = aa & (W - 1), w = aa >> LGW;
      const int hidx = S * w + i;
      const float hm = hamS[i];
#pragma unroll
      for (int mb = 0; mb < MB; ++mb) {
        const u16* rp = myslab + (mb * 16 + m16) * PSTH;
        const float th = h2f(rp[hidx]) * hm;
        const float c1 = __cosf(th), s1 = __sinf(th);
        const float tc = 2.0f * c1;
        const float c2 = tc * c1 - 1.0f, s2 = tc * s1;
        const float c3 = tc * c2 - c1,   s3 = tc * s2 - s1;
        const float c4 = tc * c3 - c2,   s4 = tc * s3 - s2;
        af[mb][0] = (_Float16)c1; af[mb][1] = (_Float16)s1;
        af[mb][2] = (_Float16)c2; af[mb][3] = (_Float16)s2;
        af[mb][4] = (_Float16)c3; af[mb][5] = (_Float16)s3;
        af[mb][6] = (_Float16)c4; af[mb][7] = (_Float16)s4;
      }
    } else {
      // section 2: g=5 tail, 4 distinct angles, direct cos/sin
      const int q0 = pg0 - S1P;
      float wm[4]; int hx[4];
#pragma unroll
      for (int u = 0; u < 4; ++u) {
        const int aa = q0 + u;
        const int i = aa & (W - 1), w = aa >> LGW;
        hx[u] = S * w + i;
        wm[u] = hamS[i] * 5.0f;
      }
#pragma unroll
      for (int mb = 0; mb < MB; ++mb) {
        const u16* rp = myslab + (mb * 16 + m16) * PSTH;
#pragma unroll
        for (int u = 0; u < 4; ++u) {
          const float ang = h2f(rp[hx[u]]) * wm[u];
          af[mb][2 * u]     = (_Float16)__cosf(ang);
          af[mb][2 * u + 1] = (_Float16)__sinf(ang);
        }
      }
    }
#pragma unroll
    for (int nb = 0; nb < NB; ++nb)
#pragma unroll
      for (int mb = 0; mb < MB; ++mb)
        acc[mb][nb] = __builtin_amdgcn_mfma_f32_16x16x32_f16(
            af[mb], bv[nb], acc[mb][nb], 0, 0, 0);
  }

  // ---- fused epilogues (C layout: row=kb*4+r, col=m16 within 16x16) ----
  if constexpr (L == 1) {
    // stage wave C-tile (64 rows x 64 cols fp16) then contiguous copy out
    u16* st = &stage1[wv * 4096];
#pragma unroll
    for (int mb = 0; mb < MB; ++mb)
#pragma unroll
      for (int nb = 0; nb < NB; ++nb) {
        const float bsv = ldf(bias, nb * 16 + m16, f32);
#pragma unroll
        for (int r = 0; r < 4; ++r)
          st[(mb * 16 + kb * 4 + r) * 64 + nb * 16 + m16] =
              f2h(acc[mb][nb][r] + bsv);
      }
    u16* gp = (u16*)out_ + (size_t)rowbase * 64;
    for (int i = lane; i < 512; i += 64)        // 512 x 16B = 8KB
      *(uint4*)(gp + i * 8) = *(const uint4*)&st[i * 8];
  } else if constexpr (L == 2) {
    // C-tile -> dead slab (stride PSTH), maxpool over 20 rows, write x1 fp16
    u16* st = myslab;
#pragma unroll
    for (int mb = 0; mb < MB; ++mb)
#pragma unroll
      for (int nb = 0; nb < NB; ++nb) {
        const float bsv = ldf(bias, ncol0 + nb * 16 + m16, f32);
#pragma unroll
        for (int r = 0; r < 4; ++r)
          st[(mb * 16 + kb * 4 + r) * PSTH + nb * 16 + m16] =
              f2h(acc[mb][nb][r] + bsv);
      }
    const int pbase = tile * 16 + wv * 4;       // 4 points per wave
#pragma unroll
    for (int j = 0; j < 4; ++j) {
      float m = -3.0e38f;
#pragma unroll
      for (int k = 0; k < 20; ++k)
        m = fmaxf(m, h2f(st[(j * 20 + k) * PSTH + lane]));
      ((u16*)out_)[(size_t)(pbase + j) * 128 + ncol0 + lane] = f2h(m);
    }
  } else {
    // in-register max/sum over 32 rows + kb butterfly -> pmax/psum partials
    const int chunk = rowbase >> 5;
#pragma unroll
    for (int nb = 0; nb < NB; ++nb) {
      const int col = ncol0 + nb * 16 + m16;
      const float bsv = ldf(bias, col, f32);
      float m = -3.0e38f, s = 0.f;
#pragma unroll
      for (int mb = 0; mb < MB; ++mb)
#pragma unroll
        for (int r = 0; r < 4; ++r) {
          const float v = acc[mb][nb][r] + bsv;
          m = fmaxf(m, v); s += v;
        }
#pragma unroll
      for (int off = 16; off <= 32; off <<= 1) {
        m = fmaxf(m, __shfl_xor(m, off, 64));
        s += __shfl_xor(s, off, 64);
      }
      if (kb == 0) {
        pmax[(size_t)chunk * 1024 + col] = m;
        psum[(size_t)chunk * 1024 + col] = s;
      }
    }
  }
}

// ---------------- segment combine: 32 chunks of 32 rows per cloud -----------
__global__ void seg2_kernel(const float* __restrict__ pmax,
                            const float* __restrict__ psum,
                            float* __restrict__ xg) {
  const int id = blockIdx.x * 256 + threadIdx.x;  // 8192
  const int b = id >> 10, col = id & 1023;
  float m = -3.0e38f, s = 0.f;
  for (int rc = 0; rc < 32; ++rc) {
    m = fmaxf(m, pmax[(size_t)(b * 32 + rc) * 1024 + col]);
    s += psum[(size_t)(b * 32 + rc) * 1024 + col];
  }
  xg[b * 2048 + col] = m;
  xg[b * 2048 + 1024 + col] = s * (1.0f / 1024.0f);
}

// ---------------- layer 4 partials: one WG per (window, batch) --------------
// c4t GLOBAL layout (angle-major): window w section-1 (g1..4 quads) at
// o*38400 + w*2048 ; g5 tail at o*38400 + 30720 + w*512.
__global__ __launch_bounds__(256) void l4_kernel(const float* __restrict__ xg,
                                                 const float* __restrict__ c4t,
                                                 float* __restrict__ part) {
  __shared__ float F[2560];
  const int t = threadIdx.x;
  const int w = blockIdx.x, b = blockIdx.y;
  const float xv = xg[b * 2048 + w * 128 + t];
  const float hm = 0.54f - 0.46f * cospif(2.0f * (float)t / 255.0f);
  const float aa = xv * hm;
  const float c1 = __cosf(aa), s1 = __sinf(aa);
  const float tc = 2.0f * c1;
  const float c2 = tc * c1 - 1.0f, s2 = tc * s1;
  const float c3 = tc * c2 - c1,   s3 = tc * s2 - s1;
  const float c4 = tc * c3 - c2,   s4 = tc * s3 - s2;
  const float a5 = aa * 5.0f;
  F[t * 8]     = c1; F[t * 8 + 1] = s1;
  F[t * 8 + 2] = c2; F[t * 8 + 3] = s2;
  F[t * 8 + 4] = c3; F[t * 8 + 5] = s3;
  F[t * 8 + 6] = c4; F[t * 8 + 7] = s4;
  F[2048 + t * 2]     = __cosf(a5);
  F[2048 + t * 2 + 1] = __sinf(a5);
  __syncthreads();
  if (t < 240) {
    const int o = t % 40, s = t / 40;
    const int f0 = s * 432;
    const int f1 = (f0 + 432 < 2560) ? (f0 + 432) : 2560;
    const float* cp1 = c4t + (size_t)o * 38400 + w * 2048;          // sec 1
    const float* cp2 = c4t + (size_t)o * 38400 + 30720 + w * 512;   // g5 tail
    float acc = 0.f;
    for (int f = f0; f < f1; f += 4) {   // 2048 boundary is float4-aligned
      const float* cpf = (f < 2048) ? (cp1 + f) : (cp2 + (f - 2048));
      const float4 cv = *(const float4*)cpf;
      const float4 fa = *(const float4*)&F[f];
      acc += fa.x * cv.x + fa.y * cv.y + fa.z * cv.z + fa.w * cv.w;
    }
    part[((b * 15 + w) * 6 + s) * 40 + o] = acc;
  }
}

__global__ void outred_kernel(const float* __restrict__ part,
                              const void* __restrict__ b4,
                              void* __restrict__ outp,
                              const int* __restrict__ dfl) {
  int t = threadIdx.x;
  if (t >= 320) return;
  const bool f32 = (*dfl != 0);
  int b = t / 40, o = t % 40;
  float s = ldf(b4, o, f32);
  for (int w = 0; w < 15; ++w)
#pragma unroll
    for (int sl = 0; sl < 6; ++sl)
      s += part[((b * 15 + w) * 6 + sl) * 40 + o];
  if (f32) ((float*)outp)[t] = s;
  else     ((u16*)outp)[t] = f2bfr(s);
}

// ---------------------------------------------------------------------------
extern "C" void kernel_launch(void* const* d_in, const int* in_sizes, int n_in,
                              void* d_out, int out_size, void* d_ws,
                              size_t ws_size, hipStream_t stream) {
  (void)in_sizes; (void)n_in; (void)out_size; (void)ws_size;
  const void* pos = d_in[0];
  // d_in[1] = batch (int32) -- clouds are sorted equal-size, used implicitly
  const void* c1 = d_in[2];
  const void* b1 = d_in[3];
  const void* c2 = d_in[4];
  const void* b2 = d_in[5];
  const void* c3 = d_in[6];
  const void* b3 = d_in[7];
  const void* c4 = d_in[8];
  const void* b4 = d_in[9];

  char* ws = (char*)d_ws;
  int* nbr   = (int*)(ws + NBR_OFF);
  int* flag  = (int*)(ws + FLAG_OFF);
  float* xg  = (float*)(ws + XG_OFF);
  float* l4p = (float*)(ws + L4P_OFF);
  u16* c1t   = (u16*)(ws + C1T_OFF);
  u16* c2t   = (u16*)(ws + C2T_OFF);
  u16* c3t   = (u16*)(ws + C3T_OFF);
  float* c4t = (float*)(ws + C4T_OFF);
  float* pmax = (float*)(ws + PMAX_OFF);
  float* psum = (float*)(ws + PSUM_OFF);
  u16* x1    = (u16*)(ws + X1_OFF);
  u16* h1    = (u16*)(ws + H1_OFF);

  detect_kernel<<<1, 64, 0, stream>>>(pos, flag);

  tkan_kernel<<<16, 256, 0, stream>>>(c1, c1t, 64, 2, 3, 64 * 64, 64, 0, flag);
  tkan_kernel<<<560, 256, 0, stream>>>(c2, c2t, 128, 7, 16, 128 * 1120, 1120, 0, flag);
  tkan_kernel<<<8960, 256, 0, stream>>>(c3, c3t, 1024, 7, 32, 1024 * 2240, 2240, 0, flag);
  tkan_kernel<<<6000, 256, 0, stream>>>(c4, c4t, 40, 15, 256, 40 * 38400, 38400, 1, flag);

  knn_kernel<<<dim3(256, 8), 256, 0, stream>>>(pos, nbr, flag);

  // L1: 640 x-blocks x 256 rows, NT=DOUT=64
  kan_kernel<1><<<640, 256, 0, stream>>>(nullptr, nbr, pos, c1t, b1, h1,
                                         nullptr, nullptr, flag);
  // L2 fused maxpool: 512 x-blocks x 320 rows (16 points), y=2 col-halves
  kan_kernel<2><<<dim3(512, 2), 256, 0, stream>>>(h1, nullptr, nullptr, c2t,
                                                  b2, x1, nullptr, nullptr, flag);
  // L3 fused segment partials: 64 x-blocks x 128 rows, y=16 col-slices
  kan_kernel<3><<<dim3(64, 16), 256, 0, stream>>>(x1, nullptr, nullptr, c3t,
                                                  b3, nullptr, pmax, psum, flag);

  seg2_kernel<<<32, 256, 0, stream>>>(pmax, psum, xg);
  l4_kernel<<<dim3(15, 8), 256, 0, stream>>>(xg, c4t, l4p);
  outred_kernel<<<1, 320, 0, stream>>>(l4p, b4, d_out, flag);
}